// Round 1
// baseline (494.655 us; speedup 1.0000x reference)
//
#include <hip/hip_runtime.h>

#define N_NODES 16384
#define N_EDGES 262144
#define BATCH   256
#define F_OUT   32
#define K_ORD   4

// ---------------- transpose: x (B,N) -> xT (N,B) ----------------
__global__ void transpose_kernel(const float* __restrict__ x, float* __restrict__ xT) {
    __shared__ float tile[32][33];
    int tx = threadIdx.x;          // 0..31
    int ty = threadIdx.y;          // 0..7
    int n0 = blockIdx.x * 32;
    int b0 = blockIdx.y * 32;
#pragma unroll
    for (int j = 0; j < 4; ++j) {
        int b = b0 + ty + j * 8;
        int n = n0 + tx;
        tile[ty + j * 8][tx] = x[(size_t)b * N_NODES + n];
    }
    __syncthreads();
#pragma unroll
    for (int j = 0; j < 4; ++j) {
        int n = n0 + ty + j * 8;
        int b = b0 + tx;
        xT[(size_t)n * BATCH + b] = tile[tx][ty + j * 8];
    }
}

// ---------------- CSR build ----------------
__global__ void hist_kernel(const int* __restrict__ rows, int* __restrict__ count) {
    int e = blockIdx.x * blockDim.x + threadIdx.x;
    if (e < N_EDGES) atomicAdd(&count[rows[e]], 1);
}

// single block of 256 threads; 64 entries per thread
__global__ void scan_kernel(int* __restrict__ count, int* __restrict__ row_ptr) {
    __shared__ int part[256];
    int t = threadIdx.x;
    int base = t * 64;
    int loc[64];
    int s = 0;
#pragma unroll
    for (int i = 0; i < 64; ++i) { loc[i] = count[base + i]; s += loc[i]; }
    part[t] = s;
    __syncthreads();
    // Hillis-Steele inclusive scan over 256 partials
    for (int d = 1; d < 256; d <<= 1) {
        int v = (t >= d) ? part[t - d] : 0;
        __syncthreads();
        part[t] += v;
        __syncthreads();
    }
    int off = part[t] - s;  // exclusive prefix
#pragma unroll
    for (int i = 0; i < 64; ++i) {
        row_ptr[base + i] = off;
        count[base + i] = off;   // becomes the scatter cursor
        off += loc[i];
    }
    if (t == 255) row_ptr[N_NODES] = off;   // == N_EDGES
}

__global__ void scatter_kernel(const int* __restrict__ rows, const int* __restrict__ cols,
                               const float* __restrict__ vals,
                               int* __restrict__ cursor,
                               int* __restrict__ csr_col, float* __restrict__ csr_val) {
    int e = blockIdx.x * blockDim.x + threadIdx.x;
    if (e < N_EDGES) {
        int r = rows[e];
        int pos = atomicAdd(&cursor[r], 1);
        csr_col[pos] = cols[e];
        csr_val[pos] = vals[e];
    }
}

// ---------------- Chebyshev step: out = c*(L@in - in) - prev ----------------
__global__ void cheb_kernel(const float* __restrict__ in, const float* __restrict__ prev,
                            float* __restrict__ out,
                            const int* __restrict__ row_ptr,
                            const float* __restrict__ csr_val, const int* __restrict__ csr_col,
                            float c) {
    int n = blockIdx.x;
    int tid = threadIdx.x;   // batch lane
    int beg = row_ptr[n], end = row_ptr[n + 1];
    float acc = 0.f;
    int e = beg;
    for (; e + 3 < end; e += 4) {
        int   c0 = csr_col[e],     c1 = csr_col[e + 1], c2 = csr_col[e + 2], c3 = csr_col[e + 3];
        float v0 = csr_val[e],     v1 = csr_val[e + 1], v2 = csr_val[e + 2], v3 = csr_val[e + 3];
        acc += v0 * in[(size_t)c0 * BATCH + tid];
        acc += v1 * in[(size_t)c1 * BATCH + tid];
        acc += v2 * in[(size_t)c2 * BATCH + tid];
        acc += v3 * in[(size_t)c3 * BATCH + tid];
    }
    for (; e < end; ++e)
        acc += csr_val[e] * in[(size_t)csr_col[e] * BATCH + tid];
    size_t idx = (size_t)n * BATCH + tid;
    float o = c * (acc - in[idx]);
    if (prev) o -= prev[idx];
    out[idx] = o;
}

// ---------------- fused: T3 = 2*(L@T2 - T2) - T1 ; y = [T0..T3] @ W^T + b ----------------
__global__ void final_kernel(const float* __restrict__ t0, const float* __restrict__ t1,
                             const float* __restrict__ t2,
                             const int* __restrict__ row_ptr,
                             const float* __restrict__ csr_val, const int* __restrict__ csr_col,
                             const float* __restrict__ weight, const float* __restrict__ bias,
                             float* __restrict__ out) {
    __shared__ float w[F_OUT * K_ORD];
    __shared__ float bb[F_OUT];
    int tid = threadIdx.x;   // batch lane
    if (tid < F_OUT * K_ORD) w[tid] = weight[tid];
    if (tid < F_OUT) bb[tid] = bias[tid];
    __syncthreads();

    int n = blockIdx.x;
    int beg = row_ptr[n], end = row_ptr[n + 1];
    float acc = 0.f;
    int e = beg;
    for (; e + 3 < end; e += 4) {
        int   c0 = csr_col[e],     c1 = csr_col[e + 1], c2 = csr_col[e + 2], c3 = csr_col[e + 3];
        float v0 = csr_val[e],     v1 = csr_val[e + 1], v2 = csr_val[e + 2], v3 = csr_val[e + 3];
        acc += v0 * t2[(size_t)c0 * BATCH + tid];
        acc += v1 * t2[(size_t)c1 * BATCH + tid];
        acc += v2 * t2[(size_t)c2 * BATCH + tid];
        acc += v3 * t2[(size_t)c3 * BATCH + tid];
    }
    for (; e < end; ++e)
        acc += csr_val[e] * t2[(size_t)csr_col[e] * BATCH + tid];

    size_t idx = (size_t)n * BATCH + tid;
    float t2v = t2[idx];
    float t3v = 2.f * (acc - t2v) - t1[idx];
    float t0v = t0[idx];
    float t1v = t1[idx];

    float* o = out + ((size_t)tid * N_NODES + n) * F_OUT;
#pragma unroll
    for (int f = 0; f < F_OUT; f += 4) {
        float4 r;
        r.x = w[(f + 0) * 4 + 0] * t0v + w[(f + 0) * 4 + 1] * t1v + w[(f + 0) * 4 + 2] * t2v + w[(f + 0) * 4 + 3] * t3v + bb[f + 0];
        r.y = w[(f + 1) * 4 + 0] * t0v + w[(f + 1) * 4 + 1] * t1v + w[(f + 1) * 4 + 2] * t2v + w[(f + 1) * 4 + 3] * t3v + bb[f + 1];
        r.z = w[(f + 2) * 4 + 0] * t0v + w[(f + 2) * 4 + 1] * t1v + w[(f + 2) * 4 + 2] * t2v + w[(f + 2) * 4 + 3] * t3v + bb[f + 2];
        r.w = w[(f + 3) * 4 + 0] * t0v + w[(f + 3) * 4 + 1] * t1v + w[(f + 3) * 4 + 2] * t2v + w[(f + 3) * 4 + 3] * t3v + bb[f + 3];
        *(float4*)(o + f) = r;
    }
}

extern "C" void kernel_launch(void* const* d_in, const int* in_sizes, int n_in,
                              void* d_out, int out_size, void* d_ws, size_t ws_size,
                              hipStream_t stream) {
    const float* x      = (const float*)d_in[0];
    const float* vals   = (const float*)d_in[1];
    const int*   rows   = (const int*)d_in[2];
    const int*   cols   = (const int*)d_in[3];
    const float* weight = (const float*)d_in[4];
    const float* bias   = (const float*)d_in[5];
    float* out = (float*)d_out;

    const size_t NB = (size_t)N_NODES * BATCH;   // 4,194,304 floats
    float* xT      = (float*)d_ws;
    float* t1      = xT + NB;
    float* t2      = t1 + NB;
    int*   row_ptr = (int*)(t2 + NB);            // N_NODES+1 (pad to 16448)
    int*   cursor  = row_ptr + 16448;            // N_NODES ints; also the histogram
    float* csr_val = (float*)(cursor + N_NODES);
    int*   csr_col = (int*)(csr_val + N_EDGES);

    hipMemsetAsync(cursor, 0, N_NODES * sizeof(int), stream);

    transpose_kernel<<<dim3(N_NODES / 32, BATCH / 32), dim3(32, 8), 0, stream>>>(x, xT);
    hist_kernel<<<N_EDGES / 256, 256, 0, stream>>>(rows, cursor);
    scan_kernel<<<1, 256, 0, stream>>>(cursor, row_ptr);
    scatter_kernel<<<N_EDGES / 256, 256, 0, stream>>>(rows, cols, vals, cursor, csr_col, csr_val);

    cheb_kernel<<<N_NODES, 256, 0, stream>>>(xT, nullptr, t1, row_ptr, csr_val, csr_col, 1.f);
    cheb_kernel<<<N_NODES, 256, 0, stream>>>(t1, xT, t2, row_ptr, csr_val, csr_col, 2.f);
    final_kernel<<<N_NODES, 256, 0, stream>>>(xT, t1, t2, row_ptr, csr_val, csr_col,
                                              weight, bias, out);
}

// Round 2
// 302.660 us; speedup vs baseline: 1.6344x; 1.6344x over previous
//
#include <hip/hip_runtime.h>

#define N_NODES 16384
#define N_EDGES 262144
#define BATCH   256
#define F_OUT   32
#define K_ORD   4

// ---------------- transpose: x (B,N) -> xT (N,B) ----------------
__global__ void transpose_kernel(const float* __restrict__ x, float* __restrict__ xT) {
    __shared__ float tile[32][33];
    int tx = threadIdx.x;          // 0..31
    int ty = threadIdx.y;          // 0..7
    int n0 = blockIdx.x * 32;
    int b0 = blockIdx.y * 32;
#pragma unroll
    for (int j = 0; j < 4; ++j) {
        int b = b0 + ty + j * 8;
        int n = n0 + tx;
        tile[ty + j * 8][tx] = x[(size_t)b * N_NODES + n];
    }
    __syncthreads();
#pragma unroll
    for (int j = 0; j < 4; ++j) {
        int n = n0 + ty + j * 8;
        int b = b0 + tx;
        xT[(size_t)n * BATCH + b] = tile[tx][ty + j * 8];
    }
}

// ---------------- CSR build ----------------
__global__ void hist_kernel(const int* __restrict__ rows, int* __restrict__ count) {
    int e = blockIdx.x * blockDim.x + threadIdx.x;
    if (e < N_EDGES) atomicAdd(&count[rows[e]], 1);
}

// single block of 256 threads; 64 entries per thread
__global__ void scan_kernel(int* __restrict__ count, int* __restrict__ row_ptr) {
    __shared__ int part[256];
    int t = threadIdx.x;
    int base = t * 64;
    int loc[64];
    int s = 0;
#pragma unroll
    for (int i = 0; i < 64; ++i) { loc[i] = count[base + i]; s += loc[i]; }
    part[t] = s;
    __syncthreads();
    // Hillis-Steele inclusive scan over 256 partials
    for (int d = 1; d < 256; d <<= 1) {
        int v = (t >= d) ? part[t - d] : 0;
        __syncthreads();
        part[t] += v;
        __syncthreads();
    }
    int off = part[t] - s;  // exclusive prefix
#pragma unroll
    for (int i = 0; i < 64; ++i) {
        row_ptr[base + i] = off;
        count[base + i] = off;   // becomes the scatter cursor
        off += loc[i];
    }
    if (t == 255) row_ptr[N_NODES] = off;   // == N_EDGES
}

__global__ void scatter_kernel(const int* __restrict__ rows, const int* __restrict__ cols,
                               const float* __restrict__ vals,
                               int* __restrict__ cursor,
                               int* __restrict__ csr_col, float* __restrict__ csr_val) {
    int e = blockIdx.x * blockDim.x + threadIdx.x;
    if (e < N_EDGES) {
        int r = rows[e];
        int pos = atomicAdd(&cursor[r], 1);
        csr_col[pos] = cols[e];
        csr_val[pos] = vals[e];
    }
}

// ---------------- Chebyshev step: out = c*(L@in - in) - prev ----------------
__global__ void cheb_kernel(const float* __restrict__ in, const float* __restrict__ prev,
                            float* __restrict__ out,
                            const int* __restrict__ row_ptr,
                            const float* __restrict__ csr_val, const int* __restrict__ csr_col,
                            float c) {
    int n = blockIdx.x;
    int tid = threadIdx.x;   // batch lane
    int beg = row_ptr[n], end = row_ptr[n + 1];
    float acc = 0.f;
    int e = beg;
    for (; e + 3 < end; e += 4) {
        int   c0 = csr_col[e],     c1 = csr_col[e + 1], c2 = csr_col[e + 2], c3 = csr_col[e + 3];
        float v0 = csr_val[e],     v1 = csr_val[e + 1], v2 = csr_val[e + 2], v3 = csr_val[e + 3];
        acc += v0 * in[(size_t)c0 * BATCH + tid];
        acc += v1 * in[(size_t)c1 * BATCH + tid];
        acc += v2 * in[(size_t)c2 * BATCH + tid];
        acc += v3 * in[(size_t)c3 * BATCH + tid];
    }
    for (; e < end; ++e)
        acc += csr_val[e] * in[(size_t)csr_col[e] * BATCH + tid];
    size_t idx = (size_t)n * BATCH + tid;
    float o = c * (acc - in[idx]);
    if (prev) o -= prev[idx];
    out[idx] = o;
}

// ---------------- fused: T3 = 2*(L@T2 - T2) - T1 ; y = [T0..T3] @ W^T + b ----------------
// Phase 1: each thread (b = tid) computes t0..t3 for node n = blockIdx.x, stages in LDS.
// Phase 2: 8 consecutive lanes cooperatively write one (b,n)'s 32 contiguous floats ->
//          128B full-line transactions per 8-lane group instead of 16B scatter per lane.
__global__ void final_kernel(const float* __restrict__ t0, const float* __restrict__ t1,
                             const float* __restrict__ t2,
                             const int* __restrict__ row_ptr,
                             const float* __restrict__ csr_val, const int* __restrict__ csr_col,
                             const float* __restrict__ weight, const float* __restrict__ bias,
                             float* __restrict__ out) {
    __shared__ float w[F_OUT * K_ORD];
    __shared__ float bb[F_OUT];
    __shared__ float tval[BATCH][4];   // [b][k] staged Chebyshev values
    int tid = threadIdx.x;             // phase-1: batch lane b
    if (tid < F_OUT * K_ORD) w[tid] = weight[tid];
    if (tid < F_OUT) bb[tid] = bias[tid];
    __syncthreads();

    int n = blockIdx.x;
    int beg = row_ptr[n], end = row_ptr[n + 1];
    float acc = 0.f;
    int e = beg;
    for (; e + 3 < end; e += 4) {
        int   c0 = csr_col[e],     c1 = csr_col[e + 1], c2 = csr_col[e + 2], c3 = csr_col[e + 3];
        float v0 = csr_val[e],     v1 = csr_val[e + 1], v2 = csr_val[e + 2], v3 = csr_val[e + 3];
        acc += v0 * t2[(size_t)c0 * BATCH + tid];
        acc += v1 * t2[(size_t)c1 * BATCH + tid];
        acc += v2 * t2[(size_t)c2 * BATCH + tid];
        acc += v3 * t2[(size_t)c3 * BATCH + tid];
    }
    for (; e < end; ++e)
        acc += csr_val[e] * t2[(size_t)csr_col[e] * BATCH + tid];

    size_t idx = (size_t)n * BATCH + tid;
    float t2v = t2[idx];
    float t3v = 2.f * (acc - t2v) - t1[idx];
    *(float4*)&tval[tid][0] = make_float4(t0[idx], t1[idx], t2v, t3v);
    __syncthreads();

    // phase 2: 2048 float4 outputs for this node; thread t does 8 of them
    const size_t nF = (size_t)n * F_OUT;
#pragma unroll
    for (int i = 0; i < 8; ++i) {
        int g  = i * 256 + tid;        // 0..2047
        int b  = g >> 3;               // batch index
        int f  = (g & 7) * 4;          // feature start
        float4 tv = *(const float4*)&tval[b][0];
        float4 r;
        r.x = w[(f + 0) * 4 + 0] * tv.x + w[(f + 0) * 4 + 1] * tv.y + w[(f + 0) * 4 + 2] * tv.z + w[(f + 0) * 4 + 3] * tv.w + bb[f + 0];
        r.y = w[(f + 1) * 4 + 0] * tv.x + w[(f + 1) * 4 + 1] * tv.y + w[(f + 1) * 4 + 2] * tv.z + w[(f + 1) * 4 + 3] * tv.w + bb[f + 1];
        r.z = w[(f + 2) * 4 + 0] * tv.x + w[(f + 2) * 4 + 1] * tv.y + w[(f + 2) * 4 + 2] * tv.z + w[(f + 2) * 4 + 3] * tv.w + bb[f + 2];
        r.w = w[(f + 3) * 4 + 0] * tv.x + w[(f + 3) * 4 + 1] * tv.y + w[(f + 3) * 4 + 2] * tv.z + w[(f + 3) * 4 + 3] * tv.w + bb[f + 3];
        *(float4*)(out + ((size_t)b * N_NODES) * F_OUT + nF + f) = r;
    }
}

extern "C" void kernel_launch(void* const* d_in, const int* in_sizes, int n_in,
                              void* d_out, int out_size, void* d_ws, size_t ws_size,
                              hipStream_t stream) {
    const float* x      = (const float*)d_in[0];
    const float* vals   = (const float*)d_in[1];
    const int*   rows   = (const int*)d_in[2];
    const int*   cols   = (const int*)d_in[3];
    const float* weight = (const float*)d_in[4];
    const float* bias   = (const float*)d_in[5];
    float* out = (float*)d_out;

    const size_t NB = (size_t)N_NODES * BATCH;   // 4,194,304 floats
    float* xT      = (float*)d_ws;
    float* t1      = xT + NB;
    float* t2      = t1 + NB;
    int*   row_ptr = (int*)(t2 + NB);            // N_NODES+1 (pad to 16448)
    int*   cursor  = row_ptr + 16448;            // N_NODES ints; also the histogram
    float* csr_val = (float*)(cursor + N_NODES);
    int*   csr_col = (int*)(csr_val + N_EDGES);

    hipMemsetAsync(cursor, 0, N_NODES * sizeof(int), stream);

    transpose_kernel<<<dim3(N_NODES / 32, BATCH / 32), dim3(32, 8), 0, stream>>>(x, xT);
    hist_kernel<<<N_EDGES / 256, 256, 0, stream>>>(rows, cursor);
    scan_kernel<<<1, 256, 0, stream>>>(cursor, row_ptr);
    scatter_kernel<<<N_EDGES / 256, 256, 0, stream>>>(rows, cols, vals, cursor, csr_col, csr_val);

    cheb_kernel<<<N_NODES, 256, 0, stream>>>(xT, nullptr, t1, row_ptr, csr_val, csr_col, 1.f);
    cheb_kernel<<<N_NODES, 256, 0, stream>>>(t1, xT, t2, row_ptr, csr_val, csr_col, 2.f);
    final_kernel<<<N_NODES, 256, 0, stream>>>(xT, t1, t2, row_ptr, csr_val, csr_col,
                                              weight, bias, out);
}